// Round 6
// baseline (404.656 us; speedup 1.0000x reference)
//
#include <hip/hip_runtime.h>

#define F 64
#define BN_EPS 1e-5f

static __device__ __forceinline__ float4 f4add(float4 a, float4 b) {
    a.x += b.x; a.y += b.y; a.z += b.z; a.w += b.w; return a;
}

// ---------------- Kernel 1: degree histogram ----------------
__global__ __launch_bounds__(256) void hist_kernel(
    const int* __restrict__ row,
    const int* __restrict__ col,
    int* __restrict__ counts,   // [N], pre-zeroed
    int nEdges)
{
    const int stride = gridDim.x * blockDim.x;
    for (int e = blockIdx.x * blockDim.x + threadIdx.x; e < nEdges; e += stride) {
        const int r = row[e];
        const int c = col[e];
        if (r != c) {
            atomicAdd(&counts[r], 1);
        }
    }
}

// ---------------- Kernel 2a: per-block scan of counts ----------------
__global__ __launch_bounds__(256) void scan1_kernel(
    const int* __restrict__ counts,
    int* __restrict__ starts,       // [N+1]
    int* __restrict__ blocksums,    // [nblocks]
    int n)
{
    __shared__ int tmp[256];
    const int t = threadIdx.x;
    const int i = blockIdx.x * 256 + t;
    const int v = (i < n) ? counts[i] : 0;
    tmp[t] = v;
    __syncthreads();
    for (int off = 1; off < 256; off <<= 1) {
        const int a = (t >= off) ? tmp[t - off] : 0;
        __syncthreads();
        tmp[t] += a;
        __syncthreads();
    }
    if (i < n) starts[i] = tmp[t] - v;     // exclusive within block
    if (t == 255) blocksums[blockIdx.x] = tmp[255];
}

// ---------------- Kernel 2b: scan of block sums (single block) ----------------
__global__ __launch_bounds__(512) void scan2_kernel(
    int* __restrict__ blocksums,
    int* __restrict__ starts,
    int nblocks, int n)
{
    __shared__ int tmp[512];
    const int t = threadIdx.x;
    const int v = (t < nblocks) ? blocksums[t] : 0;
    tmp[t] = v;
    __syncthreads();
    for (int off = 1; off < 512; off <<= 1) {
        const int a = (t >= off) ? tmp[t - off] : 0;
        __syncthreads();
        tmp[t] += a;
        __syncthreads();
    }
    if (t < nblocks) blocksums[t] = tmp[t] - v;   // exclusive
    if (t == 511) starts[n] = tmp[511];           // total kept-edge count
}

// ---------------- Kernel 2c: add block offsets; init cursor (=counts reused) ----
__global__ __launch_bounds__(256) void scan3_kernel(
    int* __restrict__ starts,
    const int* __restrict__ blocksums,
    int* __restrict__ cursor,       // counts reused as write cursor
    int n)
{
    const int i = blockIdx.x * 256 + threadIdx.x;
    if (i < n) {
        const int v = starts[i] + blocksums[i >> 8];
        starts[i] = v;
        cursor[i] = v;
    }
}

// ---------------- Kernel 3: reorder cols into CSR order (atomic cursor) -------
__global__ __launch_bounds__(256) void reorder_kernel(
    const int* __restrict__ row,
    const int* __restrict__ col,
    int* __restrict__ cursor,
    int* __restrict__ col_sorted,
    int nEdges)
{
    const int stride = gridDim.x * blockDim.x;
    for (int e = blockIdx.x * blockDim.x + threadIdx.x; e < nEdges; e += stride) {
        const int r = row[e];
        const int c = col[e];
        if (r != c) {
            const int slot = atomicAdd(&cursor[r], 1);
            col_sorted[slot] = c;
        }
    }
}

// ---------------- Kernel A: gather-aggregate (float4, direct index loads) -----
// One wave per node. lane = (group g = lane>>4, quad q = lane&15).
// Group g handles edges e+g, e+4+g, e+8+g, e+12+g per 16-edge batch; the 16
// lanes of a group load the SAME col_sorted address (broadcast). No shfl on
// the index path. 16 row-loads in flight per wave.
__global__ __launch_bounds__(256) void gather_kernel(
    const float4* __restrict__ x4,
    const int* __restrict__ starts,
    const int* __restrict__ col_sorted,
    float4* __restrict__ agg4,     // = d_out viewed as float4
    int nNodes)
{
    const int lane = threadIdx.x & 63;
    const int w = threadIdx.x >> 6;
    const int r = blockIdx.x * 4 + w;
    if (r >= nNodes) return;

    const int g = lane >> 4;   // 0..3
    const int q = lane & 15;   // 0..15

    const int s  = starts[r];
    const int en = starts[r + 1];

    const float4 vself = x4[(size_t)r * 16 + q];

    float4 a0 = {0,0,0,0}, a1 = {0,0,0,0}, a2 = {0,0,0,0}, a3 = {0,0,0,0};

    int e = s;
    for (; e + 16 <= en; e += 16) {
        const int c0 = col_sorted[e + g];        // in-bounds: e+g   <= en-1
        const int c1 = col_sorted[e + 4 + g];    //            e+7   <= en-1
        const int c2 = col_sorted[e + 8 + g];    //            e+11  <= en-1
        const int c3 = col_sorted[e + 12 + g];   //            e+15  <= en-1
        const float4 t0 = x4[(size_t)c0 * 16 + q];
        const float4 t1 = x4[(size_t)c1 * 16 + q];
        const float4 t2 = x4[(size_t)c2 * 16 + q];
        const float4 t3 = x4[(size_t)c3 * 16 + q];
        a0 = f4add(a0, t0);
        a1 = f4add(a1, t1);
        a2 = f4add(a2, t2);
        a3 = f4add(a3, t3);
    }
    for (; e + 4 <= en; e += 4) {
        const int c = col_sorted[e + g];         // e+g <= e+3 <= en-1
        a0 = f4add(a0, x4[(size_t)c * 16 + q]);
    }
    if (e + g < en) {
        const int c = col_sorted[e + g];         // guarded
        a1 = f4add(a1, x4[(size_t)c * 16 + q]);
    }

    float4 v = f4add(f4add(a0, a1), f4add(a2, a3));
    // reduce across the 4 groups: ^16 combines g0+g1 / g2+g3, ^32 combines all
    v.x += __shfl_xor(v.x, 16, 64);
    v.y += __shfl_xor(v.y, 16, 64);
    v.z += __shfl_xor(v.z, 16, 64);
    v.w += __shfl_xor(v.w, 16, 64);
    v.x += __shfl_xor(v.x, 32, 64);
    v.y += __shfl_xor(v.y, 32, 64);
    v.z += __shfl_xor(v.z, 32, 64);
    v.w += __shfl_xor(v.w, 32, 64);
    v = f4add(v, vself);

    if (g == 0) {
        agg4[(size_t)r * 16 + q] = v;
    }
}

// ---------------- Kernel B: node-per-lane MLP (block-cooperative) -------------
// One 256-node tile per block; tid = node-within-tile. Input transposed through
// LDS with barriers (uniform control flow). Layer 2 computed in 4 chunks of 16
// outputs to keep register pressure < 128 VGPR. All global reads of the tile
// precede all global writes (in-place safe within the block-private tile).
__global__ __launch_bounds__(256, 2) void mlp_kernel(
    const float* in_,               // = d_out (agg) — same buffer as out_
    const float* __restrict__ W1,
    const float* __restrict__ b1,
    const float* __restrict__ W2,
    const float* __restrict__ b2,
    float* out_,                    // = d_out (h2)
    int nNodes)
{
    __shared__ float sIn[16][256];  // 16 KiB: one 16-feature chunk, transposed

    const int tid = threadIdx.x;
    const int t0 = blockIdx.x * 256;
    const float4* in4 = (const float4*)in_;

    float acc[64];
    #pragma unroll
    for (int o = 0; o < 64; ++o) acc[o] = b1[o];

    for (int kc = 0; kc < 4; ++kc) {
        if (kc) __syncthreads();               // reads of previous chunk done
        #pragma unroll
        for (int i = 0; i < 4; ++i) {
            const int flat = i * 256 + tid;    // 0..1023
            const int node = flat >> 2;        // 0..255
            const int quad = flat & 3;         // 0..3
            int nn = t0 + node;
            if (nn >= nNodes) nn = nNodes - 1; // clamp (last block only; in-tile)
            const float4 vv = in4[(size_t)nn * 16 + kc * 4 + quad];
            sIn[quad * 4 + 0][node] = vv.x;
            sIn[quad * 4 + 1][node] = vv.y;
            sIn[quad * 4 + 2][node] = vv.z;
            sIn[quad * 4 + 3][node] = vv.w;
        }
        __syncthreads();                       // staging visible to all lanes

        for (int kk = 0; kk < 16; ++kk) {
            const float vk = sIn[kk][tid];
            const float* wr = &W1[(kc * 16 + kk) * 64];  // uniform -> s_load
            #pragma unroll
            for (int o = 0; o < 64; ++o) acc[o] = fmaf(vk, wr[o], acc[o]);
        }
    }

    // ReLU h1 in registers
    #pragma unroll
    for (int o = 0; o < 64; ++o) acc[o] = fmaxf(acc[o], 0.0f);

    const int node = t0 + tid;
    const bool valid = node < nNodes;
    float4* out4 = (float4*)out_ + (size_t)node * 16;

    #pragma unroll
    for (int oc = 0; oc < 4; ++oc) {           // 16 outputs per chunk
        float acc2[16];
        #pragma unroll
        for (int j = 0; j < 16; ++j) acc2[j] = b2[oc * 16 + j];
        #pragma unroll
        for (int k = 0; k < 64; ++k) {
            const float hk = acc[k];           // static index (fully unrolled)
            const float* wr = &W2[k * 64 + oc * 16];     // uniform -> s_load
            #pragma unroll
            for (int j = 0; j < 16; ++j) acc2[j] = fmaf(hk, wr[j], acc2[j]);
        }
        if (valid) {
            #pragma unroll
            for (int jj = 0; jj < 4; ++jj) {
                float4 vv;
                vv.x = fmaxf(acc2[jj * 4 + 0], 0.0f);
                vv.y = fmaxf(acc2[jj * 4 + 1], 0.0f);
                vv.z = fmaxf(acc2[jj * 4 + 2], 0.0f);
                vv.w = fmaxf(acc2[jj * 4 + 3], 0.0f);
                out4[oc * 4 + jj] = vv;
            }
        }
    }
}

// ---------------- Kernel C1: BN stats (sum / sumsq per feature) ---------------
__global__ __launch_bounds__(256) void stats_kernel(
    const float4* __restrict__ h,
    float* __restrict__ stats,      // [0..63]=sum, [64..127]=sumsq, pre-zeroed
    int total4)
{
    float4 ps = {0,0,0,0}, pq = {0,0,0,0};
    const int stride = gridDim.x * blockDim.x;   // multiple of 16
    for (int i = blockIdx.x * blockDim.x + threadIdx.x; i < total4; i += stride) {
        const float4 v = h[i];
        ps.x += v.x; ps.y += v.y; ps.z += v.z; ps.w += v.w;
        pq.x = fmaf(v.x, v.x, pq.x);
        pq.y = fmaf(v.y, v.y, pq.y);
        pq.z = fmaf(v.z, v.z, pq.z);
        pq.w = fmaf(v.w, v.w, pq.w);
    }
    __shared__ float4 sS[256];
    __shared__ float4 sQ[256];
    sS[threadIdx.x] = ps;
    sQ[threadIdx.x] = pq;
    __syncthreads();
    if (threadIdx.x < 16) {
        const int c = threadIdx.x;      // feature quad class
        float4 a = sS[c], b = sQ[c];
        for (int u = 1; u < 16; ++u) {
            a = f4add(a, sS[c + u * 16]);
            b = f4add(b, sQ[c + u * 16]);
        }
        atomicAdd(&stats[c * 4 + 0], a.x);
        atomicAdd(&stats[c * 4 + 1], a.y);
        atomicAdd(&stats[c * 4 + 2], a.z);
        atomicAdd(&stats[c * 4 + 3], a.w);
        atomicAdd(&stats[64 + c * 4 + 0], b.x);
        atomicAdd(&stats[64 + c * 4 + 1], b.y);
        atomicAdd(&stats[64 + c * 4 + 2], b.z);
        atomicAdd(&stats[64 + c * 4 + 3], b.w);
    }
}

// ---------------- Kernel C2: BN finalize + normalize in place (float4) --------
__global__ __launch_bounds__(256) void bn_normalize_kernel(
    float4* __restrict__ h,
    const float* __restrict__ stats,
    const float* __restrict__ gamma,
    const float* __restrict__ beta,
    int nNodes)
{
    __shared__ float sscale[F];
    __shared__ float sshift[F];
    if (threadIdx.x < F) {
        const int f = threadIdx.x;
        const float invN = 1.0f / (float)nNodes;
        const float mean = stats[f] * invN;
        const float var  = stats[F + f] * invN - mean * mean;
        const float inv  = rsqrtf(var + BN_EPS);
        const float g    = gamma[f];
        sscale[f] = inv * g;
        sshift[f] = beta[f] - mean * inv * g;
    }
    __syncthreads();

    const int total4 = nNodes * (F / 4);
    const int stride = gridDim.x * blockDim.x;
    for (int i = blockIdx.x * blockDim.x + threadIdx.x; i < total4; i += stride) {
        const int f0 = (i & 15) * 4;
        float4 v = h[i];
        v.x = fmaf(v.x, sscale[f0 + 0], sshift[f0 + 0]);
        v.y = fmaf(v.y, sscale[f0 + 1], sshift[f0 + 1]);
        v.z = fmaf(v.z, sscale[f0 + 2], sshift[f0 + 2]);
        v.w = fmaf(v.w, sscale[f0 + 3], sshift[f0 + 3]);
        h[i] = v;
    }
}

extern "C" void kernel_launch(void* const* d_in, const int* in_sizes, int n_in,
                              void* d_out, int out_size, void* d_ws, size_t ws_size,
                              hipStream_t stream)
{
    const float* x     = (const float*)d_in[0];
    const int*   eidx  = (const int*)d_in[1];   // [2, E]: row then col
    const float* W1    = (const float*)d_in[2];
    const float* b1    = (const float*)d_in[3];
    const float* W2    = (const float*)d_in[4];
    const float* b2    = (const float*)d_in[5];
    const float* gamma = (const float*)d_in[6];
    const float* beta  = (const float*)d_in[7];

    const int nNodes = in_sizes[0] / F;
    const int nEdges = in_sizes[1] / 2;
    const int* row = eidx;
    const int* col = eidx + nEdges;

    // workspace layout (4-byte elems): counts|stats contiguous for one memset
    char* wsp = (char*)d_ws;
    int*   counts     = (int*)wsp;                    wsp += (size_t)nNodes * 4;
    float* stats      = (float*)wsp;                  wsp += 128 * 4;
    int*   starts     = (int*)wsp;                    wsp += (size_t)(nNodes + 1) * 4;
    int*   blocksums  = (int*)wsp;                    wsp += 512 * 4;
    int*   col_sorted = (int*)wsp;                    wsp += (size_t)(nEdges + 16) * 4;
    float* hbuf = (float*)d_out;   // serves as agg, then h2, then final out

    const int nblocks_scan = (nNodes + 255) / 256;

    hipMemsetAsync(counts, 0, (size_t)nNodes * 4 + 128 * 4, stream);

    hist_kernel<<<2048, 256, 0, stream>>>(row, col, counts, nEdges);
    scan1_kernel<<<nblocks_scan, 256, 0, stream>>>(counts, starts, blocksums, nNodes);
    scan2_kernel<<<1, 512, 0, stream>>>(blocksums, starts, nblocks_scan, nNodes);
    scan3_kernel<<<nblocks_scan, 256, 0, stream>>>(starts, blocksums, counts, nNodes);
    reorder_kernel<<<2048, 256, 0, stream>>>(row, col, counts, col_sorted, nEdges);

    // A: one wave per node
    gather_kernel<<<(nNodes + 3) / 4, 256, 0, stream>>>(
        (const float4*)x, starts, col_sorted, (float4*)hbuf, nNodes);

    // B: one 256-node tile per block
    mlp_kernel<<<(nNodes + 255) / 256, 256, 0, stream>>>(
        hbuf, W1, b1, W2, b2, hbuf, nNodes);

    stats_kernel<<<512, 256, 0, stream>>>((const float4*)hbuf, stats, nNodes * (F / 4));
    bn_normalize_kernel<<<2048, 256, 0, stream>>>((float4*)hbuf, stats, gamma, beta, nNodes);
}

// Round 7
// 291.031 us; speedup vs baseline: 1.3904x; 1.3904x over previous
//
#include <hip/hip_runtime.h>

#define F 64
#define BN_EPS 1e-5f

static __device__ __forceinline__ float4 f4add(float4 a, float4 b) {
    a.x += b.x; a.y += b.y; a.z += b.z; a.w += b.w; return a;
}

// ---------------- Kernel 1: degree histogram + per-edge rank ----------------
__global__ __launch_bounds__(256) void hist_kernel(
    const int* __restrict__ row,
    const int* __restrict__ col,
    int* __restrict__ counts,   // [N], pre-zeroed
    int* __restrict__ rank,     // [E], coalesced write
    int nEdges)
{
    const int stride = gridDim.x * blockDim.x;
    for (int e = blockIdx.x * blockDim.x + threadIdx.x; e < nEdges; e += stride) {
        const int r = row[e];
        const int c = col[e];
        if (r != c) {
            rank[e] = atomicAdd(&counts[r], 1);
        }
    }
}

// ---------------- Kernel 2a: per-block scan of counts ----------------
__global__ __launch_bounds__(256) void scan1_kernel(
    const int* __restrict__ counts,
    int* __restrict__ starts,       // [N+1]
    int* __restrict__ blocksums,    // [nblocks]
    int n)
{
    __shared__ int tmp[256];
    const int t = threadIdx.x;
    const int i = blockIdx.x * 256 + t;
    const int v = (i < n) ? counts[i] : 0;
    tmp[t] = v;
    __syncthreads();
    for (int off = 1; off < 256; off <<= 1) {
        const int a = (t >= off) ? tmp[t - off] : 0;
        __syncthreads();
        tmp[t] += a;
        __syncthreads();
    }
    if (i < n) starts[i] = tmp[t] - v;     // exclusive within block
    if (t == 255) blocksums[blockIdx.x] = tmp[255];
}

// ---------------- Kernel 2b: scan of block sums (single block) ----------------
__global__ __launch_bounds__(512) void scan2_kernel(
    int* __restrict__ blocksums,
    int* __restrict__ starts,
    int nblocks, int n)
{
    __shared__ int tmp[512];
    const int t = threadIdx.x;
    const int v = (t < nblocks) ? blocksums[t] : 0;
    tmp[t] = v;
    __syncthreads();
    for (int off = 1; off < 512; off <<= 1) {
        const int a = (t >= off) ? tmp[t - off] : 0;
        __syncthreads();
        tmp[t] += a;
        __syncthreads();
    }
    if (t < nblocks) blocksums[t] = tmp[t] - v;   // exclusive
    if (t == 511) starts[n] = tmp[511];           // total kept-edge count
}

// ---------------- Kernel 2c: add block offsets ----------------
__global__ __launch_bounds__(256) void scan3_kernel(
    int* __restrict__ starts,
    const int* __restrict__ blocksums,
    int n)
{
    const int i = blockIdx.x * 256 + threadIdx.x;
    if (i < n) starts[i] += blocksums[i >> 8];
}

// ---------------- Kernel 3: reorder cols into CSR order (no atomics) ----------
__global__ __launch_bounds__(256) void reorder_kernel(
    const int* __restrict__ row,
    const int* __restrict__ col,
    const int* __restrict__ starts,
    const int* __restrict__ rank,
    int* __restrict__ col_sorted,
    int nEdges)
{
    const int stride = gridDim.x * blockDim.x;
    for (int e = blockIdx.x * blockDim.x + threadIdx.x; e < nEdges; e += stride) {
        const int r = row[e];
        const int c = col[e];
        if (r != c) {
            col_sorted[starts[r] + rank[e]] = c;   // fire-and-forget scatter
        }
    }
}

// ---------------- Kernel A: gather-aggregate (float4, direct index loads) -----
// One wave per node. lane = (group g = lane>>4, quad q = lane&15).
// Group g handles edges e+g, e+4+g, e+8+g, e+12+g per 16-edge batch; the 16
// lanes of a group load the SAME col_sorted address (broadcast). 16 row-loads
// in flight per wave.
__global__ __launch_bounds__(256) void gather_kernel(
    const float4* __restrict__ x4,
    const int* __restrict__ starts,
    const int* __restrict__ col_sorted,
    float4* __restrict__ agg4,     // = d_out viewed as float4
    int nNodes)
{
    const int lane = threadIdx.x & 63;
    const int w = threadIdx.x >> 6;
    const int r = blockIdx.x * 4 + w;
    if (r >= nNodes) return;

    const int g = lane >> 4;   // 0..3
    const int q = lane & 15;   // 0..15

    const int s  = starts[r];
    const int en = starts[r + 1];

    const float4 vself = x4[(size_t)r * 16 + q];

    float4 a0 = {0,0,0,0}, a1 = {0,0,0,0}, a2 = {0,0,0,0}, a3 = {0,0,0,0};

    int e = s;
    for (; e + 16 <= en; e += 16) {
        const int c0 = col_sorted[e + g];
        const int c1 = col_sorted[e + 4 + g];
        const int c2 = col_sorted[e + 8 + g];
        const int c3 = col_sorted[e + 12 + g];
        const float4 t0 = x4[(size_t)c0 * 16 + q];
        const float4 t1 = x4[(size_t)c1 * 16 + q];
        const float4 t2 = x4[(size_t)c2 * 16 + q];
        const float4 t3 = x4[(size_t)c3 * 16 + q];
        a0 = f4add(a0, t0);
        a1 = f4add(a1, t1);
        a2 = f4add(a2, t2);
        a3 = f4add(a3, t3);
    }
    for (; e + 4 <= en; e += 4) {
        const int c = col_sorted[e + g];
        a0 = f4add(a0, x4[(size_t)c * 16 + q]);
    }
    if (e + g < en) {
        const int c = col_sorted[e + g];
        a1 = f4add(a1, x4[(size_t)c * 16 + q]);
    }

    float4 v = f4add(f4add(a0, a1), f4add(a2, a3));
    v.x += __shfl_xor(v.x, 16, 64);
    v.y += __shfl_xor(v.y, 16, 64);
    v.z += __shfl_xor(v.z, 16, 64);
    v.w += __shfl_xor(v.w, 16, 64);
    v.x += __shfl_xor(v.x, 32, 64);
    v.y += __shfl_xor(v.y, 32, 64);
    v.z += __shfl_xor(v.z, 32, 64);
    v.w += __shfl_xor(v.w, 32, 64);
    v = f4add(v, vself);

    if (g == 0) {
        agg4[(size_t)r * 16 + q] = v;
    }
}

// ---------------- Kernel B: node-per-lane MLP (block-cooperative) -------------
// One 256-node tile per block; tid = node-within-tile. Input transposed through
// LDS with barriers (uniform control flow). Layer 2 computed in 4 chunks of 16
// outputs to keep register pressure < 128 VGPR.
__global__ __launch_bounds__(256, 2) void mlp_kernel(
    const float* in_,               // = d_out (agg) — same buffer as out_
    const float* __restrict__ W1,
    const float* __restrict__ b1,
    const float* __restrict__ W2,
    const float* __restrict__ b2,
    float* out_,                    // = d_out (h2)
    int nNodes)
{
    __shared__ float sIn[16][256];  // 16 KiB: one 16-feature chunk, transposed

    const int tid = threadIdx.x;
    const int t0 = blockIdx.x * 256;
    const float4* in4 = (const float4*)in_;

    float acc[64];
    #pragma unroll
    for (int o = 0; o < 64; ++o) acc[o] = b1[o];

    for (int kc = 0; kc < 4; ++kc) {
        if (kc) __syncthreads();               // reads of previous chunk done
        #pragma unroll
        for (int i = 0; i < 4; ++i) {
            const int flat = i * 256 + tid;    // 0..1023
            const int node = flat >> 2;        // 0..255
            const int quad = flat & 3;         // 0..3
            int nn = t0 + node;
            if (nn >= nNodes) nn = nNodes - 1; // clamp (last block only)
            const float4 vv = in4[(size_t)nn * 16 + kc * 4 + quad];
            sIn[quad * 4 + 0][node] = vv.x;
            sIn[quad * 4 + 1][node] = vv.y;
            sIn[quad * 4 + 2][node] = vv.z;
            sIn[quad * 4 + 3][node] = vv.w;
        }
        __syncthreads();                       // staging visible to all lanes

        for (int kk = 0; kk < 16; ++kk) {
            const float vk = sIn[kk][tid];
            const float* wr = &W1[(kc * 16 + kk) * 64];  // uniform -> s_load
            #pragma unroll
            for (int o = 0; o < 64; ++o) acc[o] = fmaf(vk, wr[o], acc[o]);
        }
    }

    // ReLU h1 in registers
    #pragma unroll
    for (int o = 0; o < 64; ++o) acc[o] = fmaxf(acc[o], 0.0f);

    const int node = t0 + tid;
    const bool valid = node < nNodes;
    float4* out4 = (float4*)out_ + (size_t)node * 16;

    #pragma unroll
    for (int oc = 0; oc < 4; ++oc) {           // 16 outputs per chunk
        float acc2[16];
        #pragma unroll
        for (int j = 0; j < 16; ++j) acc2[j] = b2[oc * 16 + j];
        #pragma unroll
        for (int k = 0; k < 64; ++k) {
            const float hk = acc[k];           // static index (fully unrolled)
            const float* wr = &W2[k * 64 + oc * 16];     // uniform -> s_load
            #pragma unroll
            for (int j = 0; j < 16; ++j) acc2[j] = fmaf(hk, wr[j], acc2[j]);
        }
        if (valid) {
            #pragma unroll
            for (int jj = 0; jj < 4; ++jj) {
                float4 vv;
                vv.x = fmaxf(acc2[jj * 4 + 0], 0.0f);
                vv.y = fmaxf(acc2[jj * 4 + 1], 0.0f);
                vv.z = fmaxf(acc2[jj * 4 + 2], 0.0f);
                vv.w = fmaxf(acc2[jj * 4 + 3], 0.0f);
                out4[oc * 4 + jj] = vv;
            }
        }
    }
}

// ---------------- Kernel C1: BN stats (sum / sumsq per feature) ---------------
__global__ __launch_bounds__(256) void stats_kernel(
    const float4* __restrict__ h,
    float* __restrict__ stats,      // [0..63]=sum, [64..127]=sumsq, pre-zeroed
    int total4)
{
    float4 ps = {0,0,0,0}, pq = {0,0,0,0};
    const int stride = gridDim.x * blockDim.x;   // multiple of 16
    for (int i = blockIdx.x * blockDim.x + threadIdx.x; i < total4; i += stride) {
        const float4 v = h[i];
        ps.x += v.x; ps.y += v.y; ps.z += v.z; ps.w += v.w;
        pq.x = fmaf(v.x, v.x, pq.x);
        pq.y = fmaf(v.y, v.y, pq.y);
        pq.z = fmaf(v.z, v.z, pq.z);
        pq.w = fmaf(v.w, v.w, pq.w);
    }
    __shared__ float4 sS[256];
    __shared__ float4 sQ[256];
    sS[threadIdx.x] = ps;
    sQ[threadIdx.x] = pq;
    __syncthreads();
    if (threadIdx.x < 16) {
        const int c = threadIdx.x;      // feature quad class
        float4 a = sS[c], b = sQ[c];
        for (int u = 1; u < 16; ++u) {
            a = f4add(a, sS[c + u * 16]);
            b = f4add(b, sQ[c + u * 16]);
        }
        atomicAdd(&stats[c * 4 + 0], a.x);
        atomicAdd(&stats[c * 4 + 1], a.y);
        atomicAdd(&stats[c * 4 + 2], a.z);
        atomicAdd(&stats[c * 4 + 3], a.w);
        atomicAdd(&stats[64 + c * 4 + 0], b.x);
        atomicAdd(&stats[64 + c * 4 + 1], b.y);
        atomicAdd(&stats[64 + c * 4 + 2], b.z);
        atomicAdd(&stats[64 + c * 4 + 3], b.w);
    }
}

// ---------------- Kernel C2: BN finalize + normalize in place (float4) --------
__global__ __launch_bounds__(256) void bn_normalize_kernel(
    float4* __restrict__ h,
    const float* __restrict__ stats,
    const float* __restrict__ gamma,
    const float* __restrict__ beta,
    int nNodes)
{
    __shared__ float sscale[F];
    __shared__ float sshift[F];
    if (threadIdx.x < F) {
        const int f = threadIdx.x;
        const float invN = 1.0f / (float)nNodes;
        const float mean = stats[f] * invN;
        const float var  = stats[F + f] * invN - mean * mean;
        const float inv  = rsqrtf(var + BN_EPS);
        const float g    = gamma[f];
        sscale[f] = inv * g;
        sshift[f] = beta[f] - mean * inv * g;
    }
    __syncthreads();

    const int total4 = nNodes * (F / 4);
    const int stride = gridDim.x * blockDim.x;
    for (int i = blockIdx.x * blockDim.x + threadIdx.x; i < total4; i += stride) {
        const int f0 = (i & 15) * 4;
        float4 v = h[i];
        v.x = fmaf(v.x, sscale[f0 + 0], sshift[f0 + 0]);
        v.y = fmaf(v.y, sscale[f0 + 1], sshift[f0 + 1]);
        v.z = fmaf(v.z, sscale[f0 + 2], sshift[f0 + 2]);
        v.w = fmaf(v.w, sscale[f0 + 3], sshift[f0 + 3]);
        h[i] = v;
    }
}

extern "C" void kernel_launch(void* const* d_in, const int* in_sizes, int n_in,
                              void* d_out, int out_size, void* d_ws, size_t ws_size,
                              hipStream_t stream)
{
    const float* x     = (const float*)d_in[0];
    const int*   eidx  = (const int*)d_in[1];   // [2, E]: row then col
    const float* W1    = (const float*)d_in[2];
    const float* b1    = (const float*)d_in[3];
    const float* W2    = (const float*)d_in[4];
    const float* b2    = (const float*)d_in[5];
    const float* gamma = (const float*)d_in[6];
    const float* beta  = (const float*)d_in[7];

    const int nNodes = in_sizes[0] / F;
    const int nEdges = in_sizes[1] / 2;
    const int* row = eidx;
    const int* col = eidx + nEdges;

    // workspace layout (4-byte elems): counts|stats contiguous for one memset
    char* wsp = (char*)d_ws;
    int*   counts     = (int*)wsp;                    wsp += (size_t)nNodes * 4;
    float* stats      = (float*)wsp;                  wsp += 128 * 4;
    int*   starts     = (int*)wsp;                    wsp += (size_t)(nNodes + 1) * 4;
    int*   blocksums  = (int*)wsp;                    wsp += 512 * 4;
    int*   rank       = (int*)wsp;                    wsp += (size_t)nEdges * 4;
    int*   col_sorted = (int*)wsp;                    wsp += (size_t)(nEdges + 16) * 4;
    float* hbuf = (float*)d_out;   // serves as agg, then h2, then final out

    const int nblocks_scan = (nNodes + 255) / 256;

    hipMemsetAsync(counts, 0, (size_t)nNodes * 4 + 128 * 4, stream);

    hist_kernel<<<2048, 256, 0, stream>>>(row, col, counts, rank, nEdges);
    scan1_kernel<<<nblocks_scan, 256, 0, stream>>>(counts, starts, blocksums, nNodes);
    scan2_kernel<<<1, 512, 0, stream>>>(blocksums, starts, nblocks_scan, nNodes);
    scan3_kernel<<<nblocks_scan, 256, 0, stream>>>(starts, blocksums, nNodes);
    reorder_kernel<<<2048, 256, 0, stream>>>(row, col, starts, rank, col_sorted, nEdges);

    // A: one wave per node
    gather_kernel<<<(nNodes + 3) / 4, 256, 0, stream>>>(
        (const float4*)x, starts, col_sorted, (float4*)hbuf, nNodes);

    // B: one 256-node tile per block
    mlp_kernel<<<(nNodes + 255) / 256, 256, 0, stream>>>(
        hbuf, W1, b1, W2, b2, hbuf, nNodes);

    stats_kernel<<<512, 256, 0, stream>>>((const float4*)hbuf, stats, nNodes * (F / 4));
    bn_normalize_kernel<<<2048, 256, 0, stream>>>((float4*)hbuf, stats, gamma, beta, nNodes);
}